// Round 1
// baseline (259.753 us; speedup 1.0000x reference)
//
#include <hip/hip_runtime.h>
#include <hip/hip_cooperative_groups.h>
#include <math.h>

namespace cg = cooperative_groups;

// Filtered Back Projection, B=2, A=181, L=512, P=1024.
// ws layout (floats):
//   [0,1024)        filt
//   [1024,2048)     hr (real impulse response)
//   [2048,2229)     cth = cos(angle + pi/2)
//   [2304,2485)     sth = sin(angle + pi/2)
//   [4096,189440)   sino_f interleaved: [a][pos][{img0,img1}]  (181*512*2)
#define OFF_FILT 0
#define OFF_HR   1024
#define OFF_CTH  2048
#define OFF_STH  2304
#define OFF_SF   4096

#define PAD   108
#define ROWE  728          // PAD + 512 + PAD
#define CHUNK 4

// cos(2*pi*x) -- v_cos_f32 takes revolutions
__device__ __forceinline__ float cos2pi(float x) {
  return __builtin_amdgcn_cosf(x);
}

// ============================================================================
// Fused cooperative kernel: filt -> hr -> conv -> backprojection.
// grid 512 x block 512, __launch_bounds__(512,4) -> VGPR<=128 -> 2 blocks/CU
// guaranteed co-resident (512 blocks == exact capacity).
// ============================================================================
__global__ __launch_bounds__(512, 4) void k_fused(const float* __restrict__ sino,
                                                  const float* __restrict__ angles,
                                                  const int* __restrict__ circ,
                                                  float* __restrict__ ws,
                                                  float* __restrict__ out) {
  cg::grid_group grid = cg::this_grid();
  __shared__ float smem[6144];   // conv: 24 KB; bp: 23.3 KB (aliased)
  const int tid = threadIdx.x;
  const int bid = blockIdx.x;
  const int lane = tid & 63;

  // ---- phase A: filt[k] (wave-per-k, 2 waves/block over 512 blocks) + trig --
  if (tid < 128) {
    const int k = bid * 2 + (tid >> 6);            // 0..1023
    float acc = 0.f;
#pragma unroll
    for (int q = 0; q < 8; q++) {
      int tt = lane + 64 * q;
      int n = (tt < 256) ? (2 * tt + 1) : (1023 - 2 * tt);
      float pin = 3.14159265358979f * (float)n;
      float cf = -1.0f / (pin * pin);
      int r = ((2 * tt + 1) * k) & 1023;
      acc = fmaf(cf, cos2pi((float)r * (1.0f / 1024.0f)), acc);
    }
#pragma unroll
    for (int o = 32; o; o >>= 1) acc += __shfl_down(acc, o, 64);
    if (lane == 0) {
      float ramp = 0.5f + 2.0f * acc;
      int ks = (k + 512) & 1023;                   // fftshift
      float hann = 0.5f - 0.5f * cos2pi((float)ks * (1.0f / 1023.0f));
      ws[OFF_FILT + k] = ramp * hann;
    }
  } else if (bid == 0 && tid < 309) {              // angle trig (tid>=128 here)
    int a = tid - 128;
    float th = angles[a] + 1.5707963267948966f;
    ws[OFF_CTH + a] = cosf(th);
    ws[OFF_STH + a] = sinf(th);
  }
  grid.sync();

  // ---- phase B: hr[m] = (1/1024) sum_k filt[k] cos(2*pi*k*m/1024) ----------
  if (tid < 128) {
    const int m = bid * 2 + (tid >> 6);            // 0..1023
    float acc = 0.f;
    int r = (lane * m) & 1023;
    const int step = (64 * m) & 1023;
#pragma unroll
    for (int q = 0; q < 16; q++) {
      acc = fmaf(ws[OFF_FILT + lane + 64 * q],
                 cos2pi((float)r * (1.0f / 1024.0f)), acc);
      r = (r + step) & 1023;
    }
#pragma unroll
    for (int o = 32; o; o >>= 1) acc += __shfl_down(acc, o, 64);
    if (lane == 0) ws[OFF_HR + m] = acc * (1.0f / 1024.0f);
  }
  grid.sync();

  // ---- phase C: row circular conv, block-per-(a,half), 8-wave split-K ------
  if (bid < 362) {
    const int a = bid >> 1;
    const int half = bid & 1;
    float* s_s0 = smem;            // 512
    float* s_s1 = smem + 512;      // 512
    float* s_hr = smem + 1024;     // 1024
    float* part = smem + 2048;     // 8 waves x 512 partials
    if (tid < 128) {
      ((float4*)s_s0)[tid] = ((const float4*)(sino + (size_t)a * 512))[tid];
    } else if (tid < 256) {
      ((float4*)s_s1)[tid - 128] =
          ((const float4*)(sino + (size_t)(181 + a) * 512))[tid - 128];
    } else {
      ((float4*)s_hr)[tid - 256] = ((const float4*)(ws + OFF_HR))[tid - 256];
    }
    __syncthreads();

    const int w = tid >> 6;                       // wave 0..7 -> taps [w*64, w*64+64)
    const int base = half * 256 + lane * 4;       // 4 output positions
    float acc0[4] = {0.f, 0.f, 0.f, 0.f};
    float acc1[4] = {0.f, 0.f, 0.f, 0.f};
    const float4* SH = (const float4*)s_hr;
    const float4* S0 = (const float4*)s_s0;
    const float4* S1 = (const float4*)s_s1;
#pragma unroll
    for (int ii = 0; ii < 8; ii++) {
      const int j8 = w * 64 + ii * 8;
      float4 sa0 = S0[j8 >> 2];
      float4 sb0 = S0[(j8 >> 2) + 1];
      float4 sa1 = S1[j8 >> 2];
      float4 sb1 = S1[(j8 >> 2) + 1];
      int wi = base - j8;
      float4 h0 = SH[((wi - 8) & 1023) >> 2];
      float4 h1 = SH[((wi - 4) & 1023) >> 2];
      float4 h2 = SH[(wi & 1023) >> 2];
      float qq[12] = {h0.x, h0.y, h0.z, h0.w, h1.x, h1.y,
                      h1.z, h1.w, h2.x, h2.y, h2.z, h2.w};
      float v0[8] = {sa0.x, sa0.y, sa0.z, sa0.w, sb0.x, sb0.y, sb0.z, sb0.w};
      float v1[8] = {sa1.x, sa1.y, sa1.z, sa1.w, sb1.x, sb1.y, sb1.z, sb1.w};
#pragma unroll
      for (int jj = 0; jj < 8; jj++) {
#pragma unroll
        for (int m = 0; m < 4; m++) {
          acc0[m] = fmaf(v0[jj], qq[8 + m - jj], acc0[m]);
          acc1[m] = fmaf(v1[jj], qq[8 + m - jj], acc1[m]);
        }
      }
    }
    // interleaved partial: part[w*512 + (pos*2 + img)]
    float* pw = part + w * 512 + lane * 8;
    ((float4*)pw)[0] = make_float4(acc0[0], acc1[0], acc0[1], acc1[1]);
    ((float4*)pw)[1] = make_float4(acc0[2], acc1[2], acc0[3], acc1[3]);
    __syncthreads();
    float s = part[tid];
#pragma unroll
    for (int ww = 1; ww < 8; ww++) s += part[ww * 512 + tid];
    ws[OFF_SF + (size_t)a * 1024 + half * 512 + tid] = s;
  }
  grid.sync();

  // ---- phase D: backprojection, block-per-row, all 181 angles, plain store -
  {
    float2* srow = (float2*)smem;                 // CHUNK * ROWE float2
    const int j = tid;
    const int i = bid;
    const float xc = (float)(i - 256);
    const float yc = (float)(j - 256);
    const float* __restrict__ cth = ws + OFF_CTH;
    const float* __restrict__ sth = ws + OFF_STH;
    float acc0 = 0.f, acc1 = 0.f;

    const float2 z2 = make_float2(0.f, 0.f);
#pragma unroll
    for (int r = 0; r < CHUNK; r++) {
      if (j < PAD) srow[r * ROWE + j] = z2;
      if (j < ROWE - PAD - 512) srow[r * ROWE + PAD + 512 + j] = z2;
    }

    const int r0 = j >> 8, r1 = r0 + 2;
    const int p0 = (j & 255) * 2;
    const int col = j & 255;
    const float4* __restrict__ G = (const float4*)(ws + OFF_SF);
    float4* SW0 = (float4*)&srow[r0 * ROWE + PAD + p0];
    float4* SW1 = (float4*)&srow[r1 * ROWE + PAD + p0];
    const int rowcap = 180;

    int A = 0;
    float4 pre0 = G[min(r0, rowcap) * 256 + col];
    float4 pre1 = G[min(r1, rowcap) * 256 + col];

    for (int c = 0; c < 46; c++) {
      __syncthreads();               // previous chunk fully consumed
      *SW0 = pre0;
      *SW1 = pre1;
      const int An = A + CHUNK;
      if (c < 45) {                  // prefetch next chunk
        pre0 = G[min(An + r0, rowcap) * 256 + col];
        pre1 = G[min(An + r1, rowcap) * 256 + col];
      }
      __syncthreads();               // writes visible
      const int nv = min(CHUNK, 181 - A);
#pragma unroll
      for (int r = 0; r < CHUNK; r++) {
        if (r >= nv) break;
        const int a = A + r;
        const float c_ = cth[a];     // uniform -> scalar loads
        const float s_ = sth[a];
        float u = fmaf(xc, c_, fmaf(yc, s_, 255.5f + (float)PAD));
        float fl = floorf(u);
        float fr = u - fl;
        int b = (int)fl;             // in [1, 725] by construction
        const float2* rp = &srow[r * ROWE];
        float2 t0 = rp[b];
        float2 t1 = rp[b + 1];
        float w0 = 1.0f - fr;
        acc0 = fmaf(w0, t0.x, fmaf(fr, t1.x, acc0));
        acc1 = fmaf(w0, t0.y, fmaf(fr, t1.y, acc1));
      }
      A = An;
    }
    const int dx = j - 256, dy = i - 256;
    const bool msk = (circ[0] != 0) && (dx * dx + dy * dy > 65536);
    const size_t o = (size_t)i * 512 + j;
    out[o] = msk ? 0.f : acc0;
    out[262144 + o] = msk ? 0.f : acc1;
  }
}

// ============================================================================
// Fallback path (proven 4-kernel pipeline) — used only if the cooperative
// launch is rejected (e.g. unsupported under graph capture).
// ============================================================================
__global__ __launch_bounds__(256) void k_filt(const float* __restrict__ angles,
                                              float* __restrict__ ws,
                                              float* __restrict__ out) {
  const int t = threadIdx.x & 63;
  const int k = blockIdx.x * 4 + (threadIdx.x >> 6);
  float acc = 0.f;
#pragma unroll
  for (int q = 0; q < 8; q++) {
    int tt = t + 64 * q;
    int n = (tt < 256) ? (2 * tt + 1) : (1023 - 2 * tt);
    float pin = 3.14159265358979f * (float)n;
    float cf = -1.0f / (pin * pin);
    int r = ((2 * tt + 1) * k) & 1023;
    acc = fmaf(cf, cos2pi((float)r * (1.0f / 1024.0f)), acc);
  }
#pragma unroll
  for (int o = 32; o; o >>= 1) acc += __shfl_down(acc, o, 64);
  if (t == 0) {
    float ramp = 0.5f + 2.0f * acc;
    int ks = (k + 512) & 1023;
    float hann = 0.5f - 0.5f * cos2pi((float)ks * (1.0f / 1023.0f));
    ws[OFF_FILT + k] = ramp * hann;
  }
  if (blockIdx.x == 0 && threadIdx.x < 181) {
    float th = angles[threadIdx.x] + 1.5707963267948966f;
    ws[OFF_CTH + threadIdx.x] = cosf(th);
    ws[OFF_STH + threadIdx.x] = sinf(th);
  }
  const float4 z4 = make_float4(0.f, 0.f, 0.f, 0.f);
  float4* o4 = (float4*)out;
  int idx = blockIdx.x * 256 + threadIdx.x;
  o4[idx] = z4;
  o4[idx + 65536] = z4;
}

__global__ __launch_bounds__(256) void k_hr(float* __restrict__ ws) {
  const int t = threadIdx.x & 63;
  const int m = blockIdx.x * 4 + (threadIdx.x >> 6);
  float acc = 0.f;
  int r = (t * m) & 1023;
  const int step = (64 * m) & 1023;
#pragma unroll
  for (int q = 0; q < 16; q++) {
    acc = fmaf(ws[OFF_FILT + t + 64 * q],
               cos2pi((float)r * (1.0f / 1024.0f)), acc);
    r = (r + step) & 1023;
  }
#pragma unroll
  for (int o = 32; o; o >>= 1) acc += __shfl_down(acc, o, 64);
  if (t == 0) ws[OFF_HR + m] = acc * (1.0f / 1024.0f);
}

__global__ __launch_bounds__(64) void k_conv(const float* __restrict__ sino,
                                             float* __restrict__ ws) {
  __shared__ float s_s0[512];
  __shared__ float s_s1[512];
  __shared__ float s_hr[1024];
  const int t = threadIdx.x;
  const int a = blockIdx.x;
  const float4* r0 = (const float4*)(sino + (size_t)a * 512);
  const float4* r1 = (const float4*)(sino + (size_t)(181 + a) * 512);
  ((float4*)s_s0)[t] = r0[t];
  ((float4*)s_s0)[t + 64] = r0[t + 64];
  ((float4*)s_s1)[t] = r1[t];
  ((float4*)s_s1)[t + 64] = r1[t + 64];
  const float4* hr4 = (const float4*)(ws + OFF_HR);
#pragma unroll
  for (int q = 0; q < 4; q++) ((float4*)s_hr)[t + 64 * q] = hr4[t + 64 * q];
  __syncthreads();

  const int base = blockIdx.y * 256 + t * 4;
  float acc0[4] = {0.f, 0.f, 0.f, 0.f};
  float acc1[4] = {0.f, 0.f, 0.f, 0.f};
  const float4* SH = (const float4*)s_hr;
  const float4* S0 = (const float4*)s_s0;
  const float4* S1 = (const float4*)s_s1;
  for (int j8 = 0; j8 < 512; j8 += 8) {
    float4 sa0 = S0[j8 >> 2];
    float4 sb0 = S0[(j8 >> 2) + 1];
    float4 sa1 = S1[j8 >> 2];
    float4 sb1 = S1[(j8 >> 2) + 1];
    int w = base - j8;
    float4 h0 = SH[((w - 8) & 1023) >> 2];
    float4 h1 = SH[((w - 4) & 1023) >> 2];
    float4 h2 = SH[(w & 1023) >> 2];
    float qq[12] = {h0.x, h0.y, h0.z, h0.w, h1.x, h1.y,
                    h1.z, h1.w, h2.x, h2.y, h2.z, h2.w};
    float v0[8] = {sa0.x, sa0.y, sa0.z, sa0.w, sb0.x, sb0.y, sb0.z, sb0.w};
    float v1[8] = {sa1.x, sa1.y, sa1.z, sa1.w, sb1.x, sb1.y, sb1.z, sb1.w};
#pragma unroll
    for (int jj = 0; jj < 8; jj++) {
#pragma unroll
      for (int m = 0; m < 4; m++) {
        acc0[m] = fmaf(v0[jj], qq[8 + m - jj], acc0[m]);
        acc1[m] = fmaf(v1[jj], qq[8 + m - jj], acc1[m]);
      }
    }
  }
  float* dst = ws + OFF_SF + (size_t)a * 1024 + base * 2;
  ((float4*)dst)[0] = make_float4(acc0[0], acc1[0], acc0[1], acc1[1]);
  ((float4*)dst)[1] = make_float4(acc0[2], acc1[2], acc0[3], acc1[3]);
}

__global__ __launch_bounds__(512) void k_bp(const float* __restrict__ ws,
                                            const int* __restrict__ circ,
                                            float* __restrict__ out) {
  __shared__ float2 srow[CHUNK * ROWE];
  const int j = threadIdx.x;
  const int i = blockIdx.x;
  const int abase = blockIdx.y * 91;
  const int acnt = min(91, 181 - abase);
  const float xc = (float)(i - 256);
  const float yc = (float)(j - 256);
  const float* __restrict__ cth = ws + OFF_CTH;
  const float* __restrict__ sth = ws + OFF_STH;
  float acc0 = 0.f, acc1 = 0.f;

  const float2 z2 = make_float2(0.f, 0.f);
#pragma unroll
  for (int r = 0; r < CHUNK; r++) {
    if (j < PAD) srow[r * ROWE + j] = z2;
    if (j < ROWE - PAD - 512) srow[r * ROWE + PAD + 512 + j] = z2;
  }

  const int r0 = j >> 8, r1 = r0 + 2;
  const int p0 = (j & 255) * 2;
  const int col = j & 255;
  const float4* __restrict__ G = (const float4*)(ws + OFF_SF);
  float4* SW0 = (float4*)&srow[r0 * ROWE + PAD + p0];
  float4* SW1 = (float4*)&srow[r1 * ROWE + PAD + p0];
  const int rowcap = abase + acnt - 1;

  int A = abase;
  float4 pre0 = G[min(A + r0, rowcap) * 256 + col];
  float4 pre1 = G[min(A + r1, rowcap) * 256 + col];

  for (int c = 0; c < 23; c++) {
    __syncthreads();
    *SW0 = pre0;
    *SW1 = pre1;
    const int An = A + CHUNK;
    if (c < 22) {
      pre0 = G[min(An + r0, rowcap) * 256 + col];
      pre1 = G[min(An + r1, rowcap) * 256 + col];
    }
    __syncthreads();
    const int nv = min(CHUNK, abase + acnt - A);
#pragma unroll
    for (int r = 0; r < CHUNK; r++) {
      if (r >= nv) break;
      const int a = A + r;
      const float c_ = cth[a];
      const float s_ = sth[a];
      float u = fmaf(xc, c_, fmaf(yc, s_, 255.5f + (float)PAD));
      float fl = floorf(u);
      float fr = u - fl;
      int b = (int)fl;
      const float2* rp = &srow[r * ROWE];
      float2 t0 = rp[b];
      float2 t1 = rp[b + 1];
      float w0 = 1.0f - fr;
      acc0 = fmaf(w0, t0.x, fmaf(fr, t1.x, acc0));
      acc1 = fmaf(w0, t0.y, fmaf(fr, t1.y, acc1));
    }
    A = An;
  }
  const int dx = j - 256, dy = i - 256;
  const bool msk = (circ[0] != 0) && (dx * dx + dy * dy > 65536);
  if (!msk) {
    const size_t o = (size_t)i * 512 + j;
    atomicAdd(&out[o], acc0);
    atomicAdd(&out[262144 + o], acc1);
  }
}

extern "C" void kernel_launch(void* const* d_in, const int* in_sizes, int n_in,
                              void* d_out, int out_size, void* d_ws, size_t ws_size,
                              hipStream_t stream) {
  const float* sino = (const float*)d_in[0];    // (2,181,512) f32
  const float* angles = (const float*)d_in[1];  // (181,) f32
  const int* circ = (const int*)d_in[2];        // scalar int
  float* ws = (float*)d_ws;
  float* out = (float*)d_out;

  void* args[] = {(void*)&sino, (void*)&angles, (void*)&circ, (void*)&ws, (void*)&out};
  hipError_t e = hipLaunchCooperativeKernel(reinterpret_cast<void*>(k_fused),
                                            dim3(512), dim3(512), args, 0, stream);
  if (e != hipSuccess) {
    (void)hipGetLastError();  // clear sticky error, use proven 4-kernel path
    hipLaunchKernelGGL(k_filt, dim3(256),    dim3(256), 0, stream, angles, ws, out);
    hipLaunchKernelGGL(k_hr,   dim3(256),    dim3(256), 0, stream, ws);
    hipLaunchKernelGGL(k_conv, dim3(181, 2), dim3(64),  0, stream, sino, ws);
    hipLaunchKernelGGL(k_bp,   dim3(512, 2), dim3(512), 0, stream, ws, circ, out);
  }
}

// Round 2
// 94.678 us; speedup vs baseline: 2.7436x; 2.7436x over previous
//
#include <hip/hip_runtime.h>
#include <math.h>

// Filtered Back Projection, B=2, A=181, L=512, P=1024.
// ws layout (floats):
//   [0,1024)        filt
//   [1024,2048)     hr (real impulse response)
//   [2048,2229)     cth = cos(angle + pi/2)
//   [2304,2485)     sth = sin(angle + pi/2)
//   [4096,189440)   sino_f interleaved: [a][pos][{img0,img1}]  (181*512*2)
#define OFF_FILT 0
#define OFF_HR   1024
#define OFF_CTH  2048
#define OFF_STH  2304
#define OFF_SF   4096

#define PAD   108
#define ROWE  728          // PAD + 512 + PAD
#define CHUNK 4            // 4*728*8 = 23296 B LDS

// cos(2*pi*x) -- v_cos_f32 takes revolutions
__device__ __forceinline__ float cos2pi(float x) {
  return __builtin_amdgcn_cosf(x);
}

// ---- filt[k] = ramp[k]*hann_shift[k]; wave-per-output, v_cos phases -------
// (d_out zeroing removed: k_bp now plain-stores every pixel)
__global__ __launch_bounds__(256) void k_filt(const float* __restrict__ angles,
                                              float* __restrict__ ws) {
  const int t = threadIdx.x & 63;
  const int k = blockIdx.x * 4 + (threadIdx.x >> 6);   // 0..1023
  float acc = 0.f;
#pragma unroll
  for (int q = 0; q < 8; q++) {
    int tt = t + 64 * q;
    int n = (tt < 256) ? (2 * tt + 1) : (1023 - 2 * tt);
    float pin = 3.14159265358979f * (float)n;
    float cf = -1.0f / (pin * pin);
    int r = ((2 * tt + 1) * k) & 1023;
    acc = fmaf(cf, cos2pi((float)r * (1.0f / 1024.0f)), acc);
  }
#pragma unroll
  for (int o = 32; o; o >>= 1) acc += __shfl_down(acc, o, 64);
  if (t == 0) {
    float ramp = 0.5f + 2.0f * acc;
    int ks = (k + 512) & 1023;                         // fftshift
    float hann = 0.5f - 0.5f * cos2pi((float)ks * (1.0f / 1023.0f));
    ws[OFF_FILT + k] = ramp * hann;
  }
  if (blockIdx.x == 0 && threadIdx.x < 181) {          // angle trig
    float th = angles[threadIdx.x] + 1.5707963267948966f;
    ws[OFF_CTH + threadIdx.x] = cosf(th);
    ws[OFF_STH + threadIdx.x] = sinf(th);
  }
}

// ---- hr[m] = (1/1024) sum_k filt[k] cos(2*pi*k*m/1024); wave-per-output ---
__global__ __launch_bounds__(256) void k_hr(float* __restrict__ ws) {
  const int t = threadIdx.x & 63;
  const int m = blockIdx.x * 4 + (threadIdx.x >> 6);   // 0..1023
  float acc = 0.f;
  int r = (t * m) & 1023;
  const int step = (64 * m) & 1023;
#pragma unroll
  for (int q = 0; q < 16; q++) {
    acc = fmaf(ws[OFF_FILT + t + 64 * q],
               cos2pi((float)r * (1.0f / 1024.0f)), acc);
    r = (r + step) & 1023;
  }
#pragma unroll
  for (int o = 32; o; o >>= 1) acc += __shfl_down(acc, o, 64);
  if (t == 0) ws[OFF_HR + m] = acc * (1.0f / 1024.0f);
}

// ---- row circular conv, 8-wave split-K, block-per-(angle,half) ------------
// Verified in round-1 fused kernel (phase C). 362 blocks x 512 threads.
// Wave w handles taps [w*64, w*64+64); LDS partial reduce at the end.
__global__ __launch_bounds__(512) void k_conv(const float* __restrict__ sino,
                                              float* __restrict__ ws) {
  __shared__ float smem[6144];   // s0 512 | s1 512 | hr 1024 | part 4096
  const int tid = threadIdx.x;
  const int a = blockIdx.x >> 1;
  const int half = blockIdx.x & 1;
  const int lane = tid & 63;
  float* s_s0 = smem;
  float* s_s1 = smem + 512;
  float* s_hr = smem + 1024;
  float* part = smem + 2048;
  if (tid < 128) {
    ((float4*)s_s0)[tid] = ((const float4*)(sino + (size_t)a * 512))[tid];
  } else if (tid < 256) {
    ((float4*)s_s1)[tid - 128] =
        ((const float4*)(sino + (size_t)(181 + a) * 512))[tid - 128];
  } else {
    ((float4*)s_hr)[tid - 256] = ((const float4*)(ws + OFF_HR))[tid - 256];
  }
  __syncthreads();

  const int w = tid >> 6;                       // wave 0..7
  const int base = half * 256 + lane * 4;       // 4 output positions
  float acc0[4] = {0.f, 0.f, 0.f, 0.f};
  float acc1[4] = {0.f, 0.f, 0.f, 0.f};
  const float4* SH = (const float4*)s_hr;
  const float4* S0 = (const float4*)s_s0;
  const float4* S1 = (const float4*)s_s1;
#pragma unroll
  for (int ii = 0; ii < 8; ii++) {
    const int j8 = w * 64 + ii * 8;
    float4 sa0 = S0[j8 >> 2];
    float4 sb0 = S0[(j8 >> 2) + 1];
    float4 sa1 = S1[j8 >> 2];
    float4 sb1 = S1[(j8 >> 2) + 1];
    int wi = base - j8;
    float4 h0 = SH[((wi - 8) & 1023) >> 2];
    float4 h1 = SH[((wi - 4) & 1023) >> 2];
    float4 h2 = SH[(wi & 1023) >> 2];
    float qq[12] = {h0.x, h0.y, h0.z, h0.w, h1.x, h1.y,
                    h1.z, h1.w, h2.x, h2.y, h2.z, h2.w};
    float v0[8] = {sa0.x, sa0.y, sa0.z, sa0.w, sb0.x, sb0.y, sb0.z, sb0.w};
    float v1[8] = {sa1.x, sa1.y, sa1.z, sa1.w, sb1.x, sb1.y, sb1.z, sb1.w};
#pragma unroll
    for (int jj = 0; jj < 8; jj++) {
#pragma unroll
      for (int m = 0; m < 4; m++) {
        acc0[m] = fmaf(v0[jj], qq[8 + m - jj], acc0[m]);
        acc1[m] = fmaf(v1[jj], qq[8 + m - jj], acc1[m]);
      }
    }
  }
  // partial: part[w*512 + (pos_local*2 + img)]
  float* pw = part + w * 512 + lane * 8;
  ((float4*)pw)[0] = make_float4(acc0[0], acc1[0], acc0[1], acc1[1]);
  ((float4*)pw)[1] = make_float4(acc0[2], acc1[2], acc0[3], acc1[3]);
  __syncthreads();
  float s = part[tid];
#pragma unroll
  for (int ww = 1; ww < 8; ww++) s += part[ww * 512 + tid];
  ws[OFF_SF + (size_t)a * 1024 + half * 512 + tid] = s;
}

// ---- backprojection: block-per-row, ALL 181 angles, plain stores ----------
// Verified in round-1 fused kernel (phase D). No atomics, no pre-zero;
// masked pixels write 0. Staging software-pipelined in CHUNK=4 row chunks.
__global__ __launch_bounds__(512) void k_bp(const float* __restrict__ ws,
                                            const int* __restrict__ circ,
                                            float* __restrict__ out) {
  __shared__ float2 srow[CHUNK * ROWE];
  const int j = threadIdx.x;
  const int i = blockIdx.x;
  const float xc = (float)(i - 256);
  const float yc = (float)(j - 256);
  const float* __restrict__ cth = ws + OFF_CTH;
  const float* __restrict__ sth = ws + OFF_STH;
  float acc0 = 0.f, acc1 = 0.f;

  // zero guard bands once; interior rewritten every chunk
  const float2 z2 = make_float2(0.f, 0.f);
#pragma unroll
  for (int r = 0; r < CHUNK; r++) {
    if (j < PAD) srow[r * ROWE + j] = z2;
    if (j < ROWE - PAD - 512) srow[r * ROWE + PAD + 512 + j] = z2;
  }

  // staging slots: thread t owns float4 slots t and t+512 of each chunk
  const int r0 = j >> 8, r1 = r0 + 2;
  const int p0 = (j & 255) * 2;
  const int col = j & 255;
  const float4* __restrict__ G = (const float4*)(ws + OFF_SF);
  float4* SW0 = (float4*)&srow[r0 * ROWE + PAD + p0];
  float4* SW1 = (float4*)&srow[r1 * ROWE + PAD + p0];
  const int rowcap = 180;

  int A = 0;
  float4 pre0 = G[min(r0, rowcap) * 256 + col];
  float4 pre1 = G[min(r1, rowcap) * 256 + col];

  for (int c = 0; c < 46; c++) {
    __syncthreads();               // previous chunk fully consumed
    *SW0 = pre0;
    *SW1 = pre1;
    const int An = A + CHUNK;
    if (c < 45) {                  // prefetch next chunk (latency hidden)
      pre0 = G[min(An + r0, rowcap) * 256 + col];
      pre1 = G[min(An + r1, rowcap) * 256 + col];
    }
    __syncthreads();               // writes visible
    const int nv = min(CHUNK, 181 - A);
#pragma unroll
    for (int r = 0; r < CHUNK; r++) {
      if (r >= nv) break;
      const int a = A + r;
      const float c_ = cth[a];     // uniform -> scalar loads
      const float s_ = sth[a];
      float u = fmaf(xc, c_, fmaf(yc, s_, 255.5f + (float)PAD));
      int b = (int)u;              // u >= 1 by construction: trunc == floor
      float fr = u - (float)b;
      const float2* rp = &srow[r * ROWE];
      float2 t0 = rp[b];
      float2 t1 = rp[b + 1];
      float w0 = 1.0f - fr;
      acc0 = fmaf(w0, t0.x, fmaf(fr, t1.x, acc0));
      acc1 = fmaf(w0, t0.y, fmaf(fr, t1.y, acc1));
    }
    A = An;
  }
  const int dx = j - 256, dy = i - 256;
  const bool msk = (circ[0] != 0) && (dx * dx + dy * dy > 65536);
  const size_t o = (size_t)i * 512 + j;
  out[o] = msk ? 0.f : acc0;
  out[262144 + o] = msk ? 0.f : acc1;
}

extern "C" void kernel_launch(void* const* d_in, const int* in_sizes, int n_in,
                              void* d_out, int out_size, void* d_ws, size_t ws_size,
                              hipStream_t stream) {
  const float* sino = (const float*)d_in[0];    // (2,181,512) f32
  const float* angles = (const float*)d_in[1];  // (181,) f32
  const int* circ = (const int*)d_in[2];        // scalar int
  float* ws = (float*)d_ws;                     // ~758 KB used
  float* out = (float*)d_out;                   // (2,512,512) f32

  hipLaunchKernelGGL(k_filt, dim3(256), dim3(256), 0, stream, angles, ws);
  hipLaunchKernelGGL(k_hr,   dim3(256), dim3(256), 0, stream, ws);
  hipLaunchKernelGGL(k_conv, dim3(362), dim3(512), 0, stream, sino, ws);
  hipLaunchKernelGGL(k_bp,   dim3(512), dim3(512), 0, stream, ws, circ, out);
}

// Round 3
// 90.443 us; speedup vs baseline: 2.8720x; 1.0468x over previous
//
#include <hip/hip_runtime.h>
#include <math.h>

// Filtered Back Projection, B=2, A=181, L=512, P=1024.
// ws layout (floats):
//   [0,1024)        filt
//   [1024,2048)     hr (real impulse response)
//   [2048,2229)     cth = cos(angle + pi/2)
//   [2304,2485)     sth = sin(angle + pi/2)
//   [4096,189440)   sino_f interleaved: [a][pos][{img0,img1}]  (181*512*2)
#define OFF_FILT 0
#define OFF_HR   1024
#define OFF_CTH  2048
#define OFF_STH  2304
#define OFF_SF   4096

#define PAD   108
#define ROWE  728          // PAD + 512 + PAD
#define CHUNK 8            // 8*728*8 = 46592 B LDS (1 block/CU)

// cos(2*pi*x) -- v_cos_f32 takes revolutions
__device__ __forceinline__ float cos2pi(float x) {
  return __builtin_amdgcn_cosf(x);
}

// ---- filt[k] = ramp[k]*hann_shift[k]; wave-per-output, v_cos phases -------
__global__ __launch_bounds__(256) void k_filt(const float* __restrict__ angles,
                                              float* __restrict__ ws) {
  const int t = threadIdx.x & 63;
  const int k = blockIdx.x * 4 + (threadIdx.x >> 6);   // 0..1023
  float acc = 0.f;
#pragma unroll
  for (int q = 0; q < 8; q++) {
    int tt = t + 64 * q;
    int n = (tt < 256) ? (2 * tt + 1) : (1023 - 2 * tt);
    float pin = 3.14159265358979f * (float)n;
    float cf = -1.0f / (pin * pin);
    int r = ((2 * tt + 1) * k) & 1023;
    acc = fmaf(cf, cos2pi((float)r * (1.0f / 1024.0f)), acc);
  }
#pragma unroll
  for (int o = 32; o; o >>= 1) acc += __shfl_down(acc, o, 64);
  if (t == 0) {
    float ramp = 0.5f + 2.0f * acc;
    int ks = (k + 512) & 1023;                         // fftshift
    float hann = 0.5f - 0.5f * cos2pi((float)ks * (1.0f / 1023.0f));
    ws[OFF_FILT + k] = ramp * hann;
  }
  if (blockIdx.x == 0 && threadIdx.x < 181) {          // angle trig
    float th = angles[threadIdx.x] + 1.5707963267948966f;
    ws[OFF_CTH + threadIdx.x] = cosf(th);
    ws[OFF_STH + threadIdx.x] = sinf(th);
  }
}

// ---- hr[m] = (1/1024) sum_k filt[k] cos(2*pi*k*m/1024); wave-per-output ---
__global__ __launch_bounds__(256) void k_hr(float* __restrict__ ws) {
  const int t = threadIdx.x & 63;
  const int m = blockIdx.x * 4 + (threadIdx.x >> 6);   // 0..1023
  float acc = 0.f;
  int r = (t * m) & 1023;
  const int step = (64 * m) & 1023;
#pragma unroll
  for (int q = 0; q < 16; q++) {
    acc = fmaf(ws[OFF_FILT + t + 64 * q],
               cos2pi((float)r * (1.0f / 1024.0f)), acc);
    r = (r + step) & 1023;
  }
#pragma unroll
  for (int o = 32; o; o >>= 1) acc += __shfl_down(acc, o, 64);
  if (t == 0) ws[OFF_HR + m] = acc * (1.0f / 1024.0f);
}

// ---- row circular conv, 8-wave split-K, block-per-(angle,half) ------------
__global__ __launch_bounds__(512) void k_conv(const float* __restrict__ sino,
                                              float* __restrict__ ws) {
  __shared__ float smem[6144];   // s0 512 | s1 512 | hr 1024 | part 4096
  const int tid = threadIdx.x;
  const int a = blockIdx.x >> 1;
  const int half = blockIdx.x & 1;
  const int lane = tid & 63;
  float* s_s0 = smem;
  float* s_s1 = smem + 512;
  float* s_hr = smem + 1024;
  float* part = smem + 2048;
  if (tid < 128) {
    ((float4*)s_s0)[tid] = ((const float4*)(sino + (size_t)a * 512))[tid];
  } else if (tid < 256) {
    ((float4*)s_s1)[tid - 128] =
        ((const float4*)(sino + (size_t)(181 + a) * 512))[tid - 128];
  } else {
    ((float4*)s_hr)[tid - 256] = ((const float4*)(ws + OFF_HR))[tid - 256];
  }
  __syncthreads();

  const int w = tid >> 6;                       // wave 0..7
  const int base = half * 256 + lane * 4;       // 4 output positions
  float acc0[4] = {0.f, 0.f, 0.f, 0.f};
  float acc1[4] = {0.f, 0.f, 0.f, 0.f};
  const float4* SH = (const float4*)s_hr;
  const float4* S0 = (const float4*)s_s0;
  const float4* S1 = (const float4*)s_s1;
#pragma unroll
  for (int ii = 0; ii < 8; ii++) {
    const int j8 = w * 64 + ii * 8;
    float4 sa0 = S0[j8 >> 2];
    float4 sb0 = S0[(j8 >> 2) + 1];
    float4 sa1 = S1[j8 >> 2];
    float4 sb1 = S1[(j8 >> 2) + 1];
    int wi = base - j8;
    float4 h0 = SH[((wi - 8) & 1023) >> 2];
    float4 h1 = SH[((wi - 4) & 1023) >> 2];
    float4 h2 = SH[(wi & 1023) >> 2];
    float qq[12] = {h0.x, h0.y, h0.z, h0.w, h1.x, h1.y,
                    h1.z, h1.w, h2.x, h2.y, h2.z, h2.w};
    float v0[8] = {sa0.x, sa0.y, sa0.z, sa0.w, sb0.x, sb0.y, sb0.z, sb0.w};
    float v1[8] = {sa1.x, sa1.y, sa1.z, sa1.w, sb1.x, sb1.y, sb1.z, sb1.w};
#pragma unroll
    for (int jj = 0; jj < 8; jj++) {
#pragma unroll
      for (int m = 0; m < 4; m++) {
        acc0[m] = fmaf(v0[jj], qq[8 + m - jj], acc0[m]);
        acc1[m] = fmaf(v1[jj], qq[8 + m - jj], acc1[m]);
      }
    }
  }
  float* pw = part + w * 512 + lane * 8;
  ((float4*)pw)[0] = make_float4(acc0[0], acc1[0], acc0[1], acc1[1]);
  ((float4*)pw)[1] = make_float4(acc0[2], acc1[2], acc0[3], acc1[3]);
  __syncthreads();
  float s = part[tid];
#pragma unroll
  for (int ww = 1; ww < 8; ww++) s += part[ww * 512 + tid];
  ws[OFF_SF + (size_t)a * 1024 + half * 512 + tid] = s;
}

// ---- backprojection: 2 rows per block (1024 thr), all 181 angles ----------
// Two output rows share the identical staged sinogram -> staging L2 traffic
// and barrier count both halve vs 1-row blocks. CHUNK=8 rows per stage;
// software-pipelined register prefetch (2 float4/thread). Plain stores.
__global__ __launch_bounds__(1024) void k_bp(const float* __restrict__ ws,
                                             const int* __restrict__ circ,
                                             float* __restrict__ out) {
  __shared__ float2 srow[CHUNK * ROWE];        // 46592 B
  const int tid = threadIdx.x;
  const int j = tid & 511;                     // column
  const int ir = tid >> 9;                     // 0/1: which of the 2 rows
  const int i = blockIdx.x * 2 + ir;
  const float xc = (float)(i - 256);
  const float yc = (float)(j - 256);
  const float* __restrict__ cth = ws + OFF_CTH;
  const float* __restrict__ sth = ws + OFF_STH;
  float acc0 = 0.f, acc1 = 0.f;

  // zero guard bands once; interior rewritten every chunk
  const float2 z2 = make_float2(0.f, 0.f);
  if (tid < PAD) {
#pragma unroll
    for (int r = 0; r < CHUNK; r++) srow[r * ROWE + tid] = z2;
  }
  if (tid < ROWE - PAD - 512) {
#pragma unroll
    for (int r = 0; r < CHUNK; r++) srow[r * ROWE + PAD + 512 + tid] = z2;
  }

  // staging: 8 rows x 256 float4 slots = 2048; thread owns slots tid, tid+1024
  const int r0 = tid >> 8, r1 = r0 + 4;        // rows 0..3 and 4..7
  const int col = tid & 255;
  const float4* __restrict__ G = (const float4*)(ws + OFF_SF);
  float4* SW0 = (float4*)&srow[r0 * ROWE + PAD + col * 2];
  float4* SW1 = (float4*)&srow[r1 * ROWE + PAD + col * 2];
  const int rowcap = 180;

  int A = 0;
  float4 pre0 = G[min(r0, rowcap) * 256 + col];
  float4 pre1 = G[min(r1, rowcap) * 256 + col];

  for (int c = 0; c < 23; c++) {               // 23*8 = 184 >= 181
    __syncthreads();               // previous chunk fully consumed
    *SW0 = pre0;
    *SW1 = pre1;
    const int An = A + CHUNK;
    if (c < 22) {                  // prefetch next chunk (latency hidden)
      pre0 = G[min(An + r0, rowcap) * 256 + col];
      pre1 = G[min(An + r1, rowcap) * 256 + col];
    }
    __syncthreads();               // writes visible
    const int nv = min(CHUNK, 181 - A);
#pragma unroll
    for (int r = 0; r < CHUNK; r++) {
      if (r >= nv) break;
      const int a = A + r;
      const float c_ = cth[a];     // uniform -> scalar loads
      const float s_ = sth[a];
      float u = fmaf(xc, c_, fmaf(yc, s_, 255.5f + (float)PAD));
      int b = (int)u;              // u >= 1 by construction: trunc == floor
      float fr = u - (float)b;
      const float2* rp = &srow[r * ROWE];
      float2 t0 = rp[b];
      float2 t1 = rp[b + 1];
      float w0 = 1.0f - fr;
      acc0 = fmaf(w0, t0.x, fmaf(fr, t1.x, acc0));
      acc1 = fmaf(w0, t0.y, fmaf(fr, t1.y, acc1));
    }
    A = An;
  }
  const int dx = j - 256, dy = i - 256;
  const bool msk = (circ[0] != 0) && (dx * dx + dy * dy > 65536);
  const size_t o = (size_t)i * 512 + j;
  out[o] = msk ? 0.f : acc0;
  out[262144 + o] = msk ? 0.f : acc1;
}

extern "C" void kernel_launch(void* const* d_in, const int* in_sizes, int n_in,
                              void* d_out, int out_size, void* d_ws, size_t ws_size,
                              hipStream_t stream) {
  const float* sino = (const float*)d_in[0];    // (2,181,512) f32
  const float* angles = (const float*)d_in[1];  // (181,) f32
  const int* circ = (const int*)d_in[2];        // scalar int
  float* ws = (float*)d_ws;                     // ~758 KB used
  float* out = (float*)d_out;                   // (2,512,512) f32

  hipLaunchKernelGGL(k_filt, dim3(256), dim3(256),  0, stream, angles, ws);
  hipLaunchKernelGGL(k_hr,   dim3(256), dim3(256),  0, stream, ws);
  hipLaunchKernelGGL(k_conv, dim3(362), dim3(512),  0, stream, sino, ws);
  hipLaunchKernelGGL(k_bp,   dim3(256), dim3(1024), 0, stream, ws, circ, out);
}

// Round 4
// 88.832 us; speedup vs baseline: 2.9241x; 1.0181x over previous
//
#include <hip/hip_runtime.h>
#include <math.h>

// Filtered Back Projection, B=2, A=181, L=512, P=1024.
// ws layout (floats):
//   [0,1024)        filt
//   [1024,2048)     hr (real impulse response)
//   [2048,2229)     cth = cos(angle + pi/2)
//   [2304,2485)     sth = sin(angle + pi/2)
//   [4096,189440)   sino_f interleaved: [a][pos][{img0,img1}]  (181*512*2)
#define OFF_FILT 0
#define OFF_HR   1024
#define OFF_CTH  2048
#define OFF_STH  2304
#define OFF_SF   4096

#define PAD   108
#define ROWE  728          // PAD + 512 + PAD
#define CHUNK 8            // 8*728*8 = 46592 B LDS (1 block/CU)

// cos(2*pi*x) -- v_cos_f32 takes revolutions
__device__ __forceinline__ float cos2pi(float x) {
  return __builtin_amdgcn_cosf(x);
}

// ---- filt[k] = ramp[k]*hann_shift[k]; wave-per-output, v_cos phases -------
__global__ __launch_bounds__(256) void k_filt(const float* __restrict__ angles,
                                              float* __restrict__ ws) {
  const int t = threadIdx.x & 63;
  const int k = blockIdx.x * 4 + (threadIdx.x >> 6);   // 0..1023
  float acc = 0.f;
#pragma unroll
  for (int q = 0; q < 8; q++) {
    int tt = t + 64 * q;
    int n = (tt < 256) ? (2 * tt + 1) : (1023 - 2 * tt);
    float pin = 3.14159265358979f * (float)n;
    float cf = -1.0f / (pin * pin);
    int r = ((2 * tt + 1) * k) & 1023;
    acc = fmaf(cf, cos2pi((float)r * (1.0f / 1024.0f)), acc);
  }
#pragma unroll
  for (int o = 32; o; o >>= 1) acc += __shfl_down(acc, o, 64);
  if (t == 0) {
    float ramp = 0.5f + 2.0f * acc;
    int ks = (k + 512) & 1023;                         // fftshift
    float hann = 0.5f - 0.5f * cos2pi((float)ks * (1.0f / 1023.0f));
    ws[OFF_FILT + k] = ramp * hann;
  }
  if (blockIdx.x == 0 && threadIdx.x < 181) {          // angle trig
    float th = angles[threadIdx.x] + 1.5707963267948966f;
    ws[OFF_CTH + threadIdx.x] = cosf(th);
    ws[OFF_STH + threadIdx.x] = sinf(th);
  }
}

// ---- hr[m] = (1/1024) sum_k filt[k] cos(2*pi*k*m/1024); wave-per-output ---
__global__ __launch_bounds__(256) void k_hr(float* __restrict__ ws) {
  const int t = threadIdx.x & 63;
  const int m = blockIdx.x * 4 + (threadIdx.x >> 6);   // 0..1023
  float acc = 0.f;
  int r = (t * m) & 1023;
  const int step = (64 * m) & 1023;
#pragma unroll
  for (int q = 0; q < 16; q++) {
    acc = fmaf(ws[OFF_FILT + t + 64 * q],
               cos2pi((float)r * (1.0f / 1024.0f)), acc);
    r = (r + step) & 1023;
  }
#pragma unroll
  for (int o = 32; o; o >>= 1) acc += __shfl_down(acc, o, 64);
  if (t == 0) ws[OFF_HR + m] = acc * (1.0f / 1024.0f);
}

// ---- row circular conv, 8-wave split-K, block-per-(angle,half) ------------
__global__ __launch_bounds__(512) void k_conv(const float* __restrict__ sino,
                                              float* __restrict__ ws) {
  __shared__ float smem[6144];   // s0 512 | s1 512 | hr 1024 | part 4096
  const int tid = threadIdx.x;
  const int a = blockIdx.x >> 1;
  const int half = blockIdx.x & 1;
  const int lane = tid & 63;
  float* s_s0 = smem;
  float* s_s1 = smem + 512;
  float* s_hr = smem + 1024;
  float* part = smem + 2048;
  if (tid < 128) {
    ((float4*)s_s0)[tid] = ((const float4*)(sino + (size_t)a * 512))[tid];
  } else if (tid < 256) {
    ((float4*)s_s1)[tid - 128] =
        ((const float4*)(sino + (size_t)(181 + a) * 512))[tid - 128];
  } else {
    ((float4*)s_hr)[tid - 256] = ((const float4*)(ws + OFF_HR))[tid - 256];
  }
  __syncthreads();

  const int w = tid >> 6;                       // wave 0..7
  const int base = half * 256 + lane * 4;       // 4 output positions
  float acc0[4] = {0.f, 0.f, 0.f, 0.f};
  float acc1[4] = {0.f, 0.f, 0.f, 0.f};
  const float4* SH = (const float4*)s_hr;
  const float4* S0 = (const float4*)s_s0;
  const float4* S1 = (const float4*)s_s1;
#pragma unroll
  for (int ii = 0; ii < 8; ii++) {
    const int j8 = w * 64 + ii * 8;
    float4 sa0 = S0[j8 >> 2];
    float4 sb0 = S0[(j8 >> 2) + 1];
    float4 sa1 = S1[j8 >> 2];
    float4 sb1 = S1[(j8 >> 2) + 1];
    int wi = base - j8;
    float4 h0 = SH[((wi - 8) & 1023) >> 2];
    float4 h1 = SH[((wi - 4) & 1023) >> 2];
    float4 h2 = SH[(wi & 1023) >> 2];
    float qq[12] = {h0.x, h0.y, h0.z, h0.w, h1.x, h1.y,
                    h1.z, h1.w, h2.x, h2.y, h2.z, h2.w};
    float v0[8] = {sa0.x, sa0.y, sa0.z, sa0.w, sb0.x, sb0.y, sb0.z, sb0.w};
    float v1[8] = {sa1.x, sa1.y, sa1.z, sa1.w, sb1.x, sb1.y, sb1.z, sb1.w};
#pragma unroll
    for (int jj = 0; jj < 8; jj++) {
#pragma unroll
      for (int m = 0; m < 4; m++) {
        acc0[m] = fmaf(v0[jj], qq[8 + m - jj], acc0[m]);
        acc1[m] = fmaf(v1[jj], qq[8 + m - jj], acc1[m]);
      }
    }
  }
  float* pw = part + w * 512 + lane * 8;
  ((float4*)pw)[0] = make_float4(acc0[0], acc1[0], acc0[1], acc1[1]);
  ((float4*)pw)[1] = make_float4(acc0[2], acc1[2], acc0[3], acc1[3]);
  __syncthreads();
  float s = part[tid];
#pragma unroll
  for (int ww = 1; ww < 8; ww++) s += part[ww * 512 + tid];
  ws[OFF_SF + (size_t)a * 1024 + half * 512 + tid] = s;
}

// ---- backprojection: 2 rows per block (1024 thr), all 181 angles ----------
// Wave-uniform circle skip: waves whose 64 columns are fully outside the
// circle skip the per-angle body (15% of waves) but keep ALL staging and
// barrier duties (no divergence hazard, no deadlock). fract(u) replaces the
// cvt/cvt/sub fraction sequence.
__global__ __launch_bounds__(1024) void k_bp(const float* __restrict__ ws,
                                             const int* __restrict__ circ,
                                             float* __restrict__ out) {
  __shared__ float2 srow[CHUNK * ROWE];        // 46592 B
  const int tid = threadIdx.x;
  const int j = tid & 511;                     // column
  const int ir = tid >> 9;                     // 0/1: which of the 2 rows
  const int i = blockIdx.x * 2 + ir;
  const float xc = (float)(i - 256);
  const float yc = (float)(j - 256);
  const float* __restrict__ cth = ws + OFF_CTH;
  const float* __restrict__ sth = ws + OFF_STH;
  float acc0 = 0.f, acc1 = 0.f;

  // circle mask; wave-uniform skip flag for fully-masked waves
  const int circv = circ[0];
  const int dx = j - 256, dy = i - 256;
  const bool msk = (circv != 0) && (dx * dx + dy * dy > 65536);
  const bool wskip = (__all((int)msk) != 0);

  // zero guard bands once; interior rewritten every chunk
  const float2 z2 = make_float2(0.f, 0.f);
  if (tid < PAD) {
#pragma unroll
    for (int r = 0; r < CHUNK; r++) srow[r * ROWE + tid] = z2;
  }
  if (tid < ROWE - PAD - 512) {
#pragma unroll
    for (int r = 0; r < CHUNK; r++) srow[r * ROWE + PAD + 512 + tid] = z2;
  }

  // staging: 8 rows x 256 float4 slots = 2048; thread owns slots tid, tid+1024
  const int r0 = tid >> 8, r1 = r0 + 4;        // rows 0..3 and 4..7
  const int col = tid & 255;
  const float4* __restrict__ G = (const float4*)(ws + OFF_SF);
  float4* SW0 = (float4*)&srow[r0 * ROWE + PAD + col * 2];
  float4* SW1 = (float4*)&srow[r1 * ROWE + PAD + col * 2];
  const int rowcap = 180;

  int A = 0;
  float4 pre0 = G[min(r0, rowcap) * 256 + col];
  float4 pre1 = G[min(r1, rowcap) * 256 + col];

  for (int c = 0; c < 23; c++) {               // 23*8 = 184 >= 181
    __syncthreads();               // previous chunk fully consumed
    *SW0 = pre0;
    *SW1 = pre1;
    const int An = A + CHUNK;
    if (c < 22) {                  // prefetch next chunk (latency hidden)
      pre0 = G[min(An + r0, rowcap) * 256 + col];
      pre1 = G[min(An + r1, rowcap) * 256 + col];
    }
    __syncthreads();               // writes visible
    if (!wskip) {                  // wave-uniform: masked waves idle here
      const int nv = min(CHUNK, 181 - A);
#pragma unroll
      for (int r = 0; r < CHUNK; r++) {
        if (r >= nv) break;
        const int a = A + r;
        const float c_ = cth[a];   // uniform -> scalar loads
        const float s_ = sth[a];
        float u = fmaf(xc, c_, fmaf(yc, s_, 255.5f + (float)PAD));
        int b = (int)u;            // u >= 1 by construction: trunc == floor
        float fr = __builtin_amdgcn_fractf(u);   // v_fract_f32
        const float2* rp = &srow[r * ROWE];
        float2 t0 = rp[b];
        float2 t1 = rp[b + 1];
        float w0 = 1.0f - fr;
        acc0 = fmaf(w0, t0.x, fmaf(fr, t1.x, acc0));
        acc1 = fmaf(w0, t0.y, fmaf(fr, t1.y, acc1));
      }
    }
    A = An;
  }
  const size_t o = (size_t)i * 512 + j;
  out[o] = msk ? 0.f : acc0;
  out[262144 + o] = msk ? 0.f : acc1;
}

extern "C" void kernel_launch(void* const* d_in, const int* in_sizes, int n_in,
                              void* d_out, int out_size, void* d_ws, size_t ws_size,
                              hipStream_t stream) {
  const float* sino = (const float*)d_in[0];    // (2,181,512) f32
  const float* angles = (const float*)d_in[1];  // (181,) f32
  const int* circ = (const int*)d_in[2];        // scalar int
  float* ws = (float*)d_ws;                     // ~758 KB used
  float* out = (float*)d_out;                   // (2,512,512) f32

  hipLaunchKernelGGL(k_filt, dim3(256), dim3(256),  0, stream, angles, ws);
  hipLaunchKernelGGL(k_hr,   dim3(256), dim3(256),  0, stream, ws);
  hipLaunchKernelGGL(k_conv, dim3(362), dim3(512),  0, stream, sino, ws);
  hipLaunchKernelGGL(k_bp,   dim3(256), dim3(1024), 0, stream, ws, circ, out);
}